// Round 9
// baseline (177.757 us; speedup 1.0000x reference)
//
#include <hip/hip_runtime.h>
#include <cmath>

// RetinaNet focal + smooth-L1 loss — 3-kernel split.
// R1..R8 finding: every variant with branch-guarded or LDS-dependent cls
// loads lands at 52-58us (1 outstanding load/wave, VGPR 24-28 = zero load
// clustering). R9: focal kernel is a branchless flat streaming reduction —
// labels precomputed to global by an assign kernel, 8 label + 8 cls loads
// issued straight-line per thread (16 deep on vmcnt), math fully masked.
// B=4, C=80 fixed by reference.

typedef float fvec4 __attribute__((ext_vector_type(4)));

// ---------------- kernel A: anchor assignment + reg loss ----------------
__global__ __launch_bounds__(256) void retina_assign(
    const float* __restrict__ reg_heads,   // (B, N, 4)
    const float* __restrict__ anchors,     // (B, N, 4) — broadcast across B
    const float* __restrict__ annots,      // (B, M, 5)
    float* __restrict__ ws,                // [0..3] cls [4..7] reg [8..11] pos
    float* __restrict__ labf,              // (B, N) labels out
    int N, int M, int B)
{
    const int b = blockIdx.y;
    const int t = threadIdx.x;
    const int n = (blockIdx.x << 8) + t;

    __shared__ float s_ann[5 * 64];
    __shared__ float s_red[8];

    for (int i = t; i < 5 * M; i += 256)
        s_ann[i] = annots[(size_t)b * 5 * M + i];
    __syncthreads();

    float reg_acc = 0.0f;
    float pos_cnt = 0.0f;
    float label   = -1.0f;
    if (n < N) {
        const float4 a = *(const float4*)(anchors + (size_t)n * 4); // plane 0
        const bool inside = (a.x > 0.0f) && (a.y > 0.0f) &&
                            (a.z < 640.0f) && (a.w < 640.0f);
        if (inside) {
            const float area_a = (a.z - a.x) * (a.w - a.y);
            float best = -3.0e38f;
            int   bi   = 0;
            bool  any  = false;
            for (int m = 0; m < M; ++m) {
                const float gx1 = s_ann[m*5+0], gy1 = s_ann[m*5+1];
                const float gx2 = s_ann[m*5+2], gy2 = s_ann[m*5+3];
                const float gc  = s_ann[m*5+4];
                float v = -1.0f;
                if (gc >= 0.0f) {
                    any = true;
                    const float iw = fmaxf(fminf(a.z, gx2) - fmaxf(a.x, gx1), 0.0f);
                    const float ih = fmaxf(fminf(a.w, gy2) - fmaxf(a.y, gy1), 0.0f);
                    const float inter = iw * ih;
                    v = inter / (area_a + (gx2 - gx1) * (gy2 - gy1) - inter);
                }
                if (v > best) { best = v; bi = m; }   // first-max == jnp.argmax
            }
            if (any) {
                if (best < 0.4f)      label = 0.0f;
                else if (best > 0.5f) label = s_ann[bi*5+4] + 1.0f;
            }
            if (label > 0.0f) {
                pos_cnt = 1.0f;
                const float aw = a.z - a.x, ah = a.w - a.y;
                const float acx = a.x + 0.5f * aw, acy = a.y + 0.5f * ah;
                const float gw = fmaxf(s_ann[bi*5+2] - s_ann[bi*5+0], 1.0f);
                const float gh = fmaxf(s_ann[bi*5+3] - s_ann[bi*5+1], 1.0f);
                const float gcx = s_ann[bi*5+0] + 0.5f * gw;
                const float gcy = s_ann[bi*5+1] + 0.5f * gh;
                const float tx = (gcx - acx) / aw * 10.0f;
                const float ty = (gcy - acy) / ah * 10.0f;
                const float tw = __logf(gw / aw) * 5.0f;
                const float th = __logf(gh / ah) * 5.0f;
                const float4 r = *(const float4*)(reg_heads + ((size_t)b * N + n) * 4);
                const float dx[4] = { fabsf(r.x - tx), fabsf(r.y - ty),
                                      fabsf(r.z - tw), fabsf(r.w - th) };
                #pragma unroll
                for (int j = 0; j < 4; ++j) {
                    const float x = dx[j];
                    reg_acc += (x < (1.0f / 9.0f)) ? 4.5f * x * x
                                                   : x - (1.0f / 18.0f);
                }
            }
        }
        labf[(size_t)b * N + n] = label;
    }

    const int lane = t & 63, wid = t >> 6;
    #pragma unroll
    for (int off = 32; off > 0; off >>= 1) {
        reg_acc += __shfl_down(reg_acc, off, 64);
        pos_cnt += __shfl_down(pos_cnt, off, 64);
    }
    if (lane == 0) { s_red[wid] = reg_acc; s_red[4 + wid] = pos_cnt; }
    __syncthreads();
    if (t == 0) {
        const float r = s_red[0] + s_red[1] + s_red[2] + s_red[3];
        const float p = s_red[4] + s_red[5] + s_red[6] + s_red[7];
        if (r != 0.0f) atomicAdd(&ws[4 + b], r);
        if (p != 0.0f) atomicAdd(&ws[8 + b], p);
    }
}

// ---------------- kernel B: branchless streaming focal reduction ----------------
// Each block: 2048 consecutive float4s of image b; each thread 8, issued as
// 8 label loads + 8 cls loads straight-line (16 outstanding), masked math.
__global__ __launch_bounds__(256, 4) void retina_focal(
    const float* __restrict__ cls_heads,   // (B, N, 80)
    const float* __restrict__ labf,        // (B, N)
    float* __restrict__ ws,                // [0..3] cls sums
    int N, int B)
{
    const int b = blockIdx.y;
    const int t = threadIdx.x;
    const int E = N * 20;                       // float4s per image
    const int base = (blockIdx.x << 11) + t;    // 2048 per block

    const float* lab_b = labf + (size_t)b * N;
    const fvec4* cls_b = (const fvec4*)(cls_heads + (size_t)b * N * 80);

    // address setup — no control flow
    int   ec[8]; float inr[8];
    #pragma unroll
    for (int k = 0; k < 8; ++k) {
        const int e = base + (k << 8);
        const int ok = (e < E);
        inr[k] = ok ? 1.0f : 0.0f;
        ec[k]  = ok ? e : 0;
    }
    int a[8], c4[8];
    #pragma unroll
    for (int k = 0; k < 8; ++k) { a[k] = ec[k] / 20; c4[k] = ec[k] - 20 * a[k]; }

    // 8 label loads, then 8 cls loads — all independent, straight-line
    float lab[8];
    #pragma unroll
    for (int k = 0; k < 8; ++k) lab[k] = lab_b[a[k]];
    fvec4 p4[8];
    #pragma unroll
    for (int k = 0; k < 8; ++k) p4[k] = cls_b[ec[k]];

    float cls_acc = 0.0f;
    #pragma unroll
    for (int k = 0; k < 8; ++k) {
        const float mask = (lab[k] >= 0.0f) ? inr[k] : 0.0f;
        const float pv[4] = { p4[k].x, p4[k].y, p4[k].z, p4[k].w };
        const float cb = (float)(c4[k] * 4 + 1);
        float local = 0.0f;
        #pragma unroll
        for (int j = 0; j < 4; ++j) {
            const float p = fminf(fmaxf(pv[j], 1.0e-4f), 1.0f - 1.0e-4f);
            const bool  is_pos = (lab[k] == cb + (float)j);
            const float pt     = is_pos ? p : 1.0f - p;
            const float alpha  = is_pos ? 0.25f : 0.75f;
            const float om     = 1.0f - pt;
            local += alpha * om * om * (-__logf(pt));
        }
        cls_acc += mask * local;
    }

    // block reduction
    __shared__ float s_red[4];
    const int lane = t & 63, wid = t >> 6;
    #pragma unroll
    for (int off = 32; off > 0; off >>= 1)
        cls_acc += __shfl_down(cls_acc, off, 64);
    if (lane == 0) s_red[wid] = cls_acc;
    __syncthreads();
    if (t == 0) {
        const float c = s_red[0] + s_red[1] + s_red[2] + s_red[3];
        if (c != 0.0f) atomicAdd(&ws[b], c);
    }
}

// ---------------- kernel C: finalize ----------------
__global__ void retina_final(const float* __restrict__ ws,
                             float* __restrict__ out, int B)
{
    if (threadIdx.x == 0 && blockIdx.x == 0) {
        float cl = 0.0f, rl = 0.0f, nv = 0.0f;
        for (int b = 0; b < B; ++b) {
            const float pos = ws[8 + b];
            if (pos > 0.0f) {
                cl += ws[b]     / fmaxf(pos, 1.0f);
                rl += ws[4 + b] / fmaxf(4.0f * pos, 1.0f);
                nv += 1.0f;
            }
        }
        const float n = fmaxf(nv, 1.0f);
        out[0] = cl / n;
        out[1] = rl / n;
    }
}

extern "C" void kernel_launch(void* const* d_in, const int* in_sizes, int n_in,
                              void* d_out, int out_size, void* d_ws, size_t ws_size,
                              hipStream_t stream) {
    const float* cls = (const float*)d_in[0];
    const float* reg = (const float*)d_in[1];
    const float* anc = (const float*)d_in[2];
    const float* ann = (const float*)d_in[3];

    const int B = 4;
    const int N = in_sizes[1] / (4 * B);      // 76725
    const int M = in_sizes[3] / (5 * B);      // 16
    float* ws   = (float*)d_ws;
    float* labf = ws + 16;                    // (B,N) labels, 1.2 MB

    (void)hipMemsetAsync(d_ws, 0, 12 * sizeof(float), stream);

    dim3 gridA((N + 255) / 256, B);           // 300 x 4
    retina_assign<<<gridA, 256, 0, stream>>>(reg, anc, ann, ws, labf, N, M, B);

    const int E = N * 20;                     // 1,534,500 float4s per image
    dim3 gridB((E + 2047) / 2048, B);         // 750 x 4 = 3000 blocks
    retina_focal<<<gridB, 256, 0, stream>>>(cls, labf, ws, N, B);

    retina_final<<<1, 64, 0, stream>>>(ws, (float*)d_out, B);
}

// Round 10
// 169.196 us; speedup vs baseline: 1.0506x; 1.0506x over previous
//
#include <hip/hip_runtime.h>
#include <cmath>

// RetinaNet focal + smooth-L1 loss. Best skeleton = R5 (split main+finalize,
// 256-anchor tiles, ~164.6us total). R10 change: phase 2 = two half-tiles of
// 10 FULLY-UNROLLED UNCONDITIONAL straight-line loads (10 ds_read labels into
// named regs, then 10 independent global dwordx4, then masked math). Every
// prior MLP attempt (ring/k%PF/guarded loads) was serializable by the
// compiler; this one has no conditionals, no array indexing, nothing to sink.
// B=4, C=80 fixed by reference.

typedef float fvec4 __attribute__((ext_vector_type(4)));

__global__ __launch_bounds__(256) void retina_main(
    const float* __restrict__ cls_heads,   // (B, N, 80)
    const float* __restrict__ reg_heads,   // (B, N, 4)
    const float* __restrict__ anchors,     // (B, N, 4) — broadcast across B
    const float* __restrict__ annots,      // (B, M, 5)
    float* __restrict__ ws,                // [0..3] cls [4..7] reg [8..11] pos
    int N, int M, int B)
{
    const int b  = blockIdx.y;
    const int n0 = blockIdx.x << 8;        // 256 anchors per block
    const int t  = threadIdx.x;

    __shared__ float s_lab[256];
    __shared__ float s_red[12];

    // ---- phase 1: per-anchor assignment; annots read straight from global
    // (320 B, uniform addresses -> scalar/L2-broadcast). No staging barrier.
    float reg_acc = 0.0f;
    float pos_cnt = 0.0f;
    float label   = -1.0f;
    const int n = n0 + t;
    if (n < N) {
        const float4 a = *(const float4*)(anchors + (size_t)n * 4); // plane 0
        const bool inside = (a.x > 0.0f) && (a.y > 0.0f) &&
                            (a.z < 640.0f) && (a.w < 640.0f);
        if (inside) {
            const float* ann = annots + (size_t)b * 5 * M;
            const float area_a = (a.z - a.x) * (a.w - a.y);
            float best = -3.0e38f;
            int   bi   = 0;
            bool  any  = false;
            for (int m = 0; m < M; ++m) {
                const float gx1 = ann[m*5+0], gy1 = ann[m*5+1];
                const float gx2 = ann[m*5+2], gy2 = ann[m*5+3];
                const float gc  = ann[m*5+4];
                float v = -1.0f;
                if (gc >= 0.0f) {
                    any = true;
                    const float iw = fmaxf(fminf(a.z, gx2) - fmaxf(a.x, gx1), 0.0f);
                    const float ih = fmaxf(fminf(a.w, gy2) - fmaxf(a.y, gy1), 0.0f);
                    const float inter = iw * ih;
                    v = inter / (area_a + (gx2 - gx1) * (gy2 - gy1) - inter);
                }
                if (v > best) { best = v; bi = m; }   // first-max == jnp.argmax
            }
            if (any) {
                if (best < 0.4f)      label = 0.0f;
                else if (best > 0.5f) label = ann[bi*5+4] + 1.0f;
            }
            if (label > 0.0f) {
                pos_cnt = 1.0f;
                const float aw = a.z - a.x, ah = a.w - a.y;
                const float acx = a.x + 0.5f * aw, acy = a.y + 0.5f * ah;
                const float gw = fmaxf(ann[bi*5+2] - ann[bi*5+0], 1.0f);
                const float gh = fmaxf(ann[bi*5+3] - ann[bi*5+1], 1.0f);
                const float gcx = ann[bi*5+0] + 0.5f * gw;
                const float gcy = ann[bi*5+1] + 0.5f * gh;
                const float tx = (gcx - acx) / aw * 10.0f;
                const float ty = (gcy - acy) / ah * 10.0f;
                const float tw = __logf(gw / aw) * 5.0f;
                const float th = __logf(gh / ah) * 5.0f;
                const float4 r = *(const float4*)(reg_heads + ((size_t)b * N + n) * 4);
                const float dx[4] = { fabsf(r.x - tx), fabsf(r.y - ty),
                                      fabsf(r.z - tw), fabsf(r.w - th) };
                #pragma unroll
                for (int j = 0; j < 4; ++j) {
                    const float x = dx[j];
                    reg_acc += (x < (1.0f / 9.0f)) ? 4.5f * x * x
                                                   : x - (1.0f / 18.0f);
                }
            }
        }
    }
    s_lab[t] = label;        // all 256 threads write (label=-1 for n>=N)
    const int anyValid = __syncthreads_or(label >= 0.0f ? 1 : 0);

    // ---- phase 2: 256 anchors x 20 float4 = 5120 float4s, 20/thread in two
    // halves of 10. Per half: 10 LDS label reads -> 10 independent global
    // dwordx4 (straight-line, 10 outstanding on vmcnt) -> masked math.
    float cls_acc = 0.0f;
    if (anyValid) {
        const int tile   = (N - n0 < 256) ? (N - n0) : 256;
        const int valid4 = tile * 20;
        const float* cls_base = cls_heads + ((size_t)b * N + n0) * 80;

        #pragma unroll
        for (int h = 0; h < 2; ++h) {
            // labels (LDS, lgkmcnt — doesn't touch vmcnt)
            float lb0,lb1,lb2,lb3,lb4,lb5,lb6,lb7,lb8,lb9;
            {
                const int e0 = t + (h * 10 + 0) * 256;
                lb0 = s_lab[(e0            ) / 20];
                lb1 = s_lab[(e0 +  1 * 256 ) / 20];
                lb2 = s_lab[(e0 +  2 * 256 ) / 20];
                lb3 = s_lab[(e0 +  3 * 256 ) / 20];
                lb4 = s_lab[(e0 +  4 * 256 ) / 20];
                lb5 = s_lab[(e0 +  5 * 256 ) / 20];
                lb6 = s_lab[(e0 +  6 * 256 ) / 20];
                lb7 = s_lab[(e0 +  7 * 256 ) / 20];
                lb8 = s_lab[(e0 +  8 * 256 ) / 20];
                lb9 = s_lab[(e0 +  9 * 256 ) / 20];
            }
            // addresses (clamp tail to 0 — masked out via s_lab == -1)
            const int e0 = t + (h * 10 + 0) * 256;
            #define CLMP(E) (((E) < valid4) ? (E) : 0)
            const int a0 = CLMP(e0), a1 = CLMP(e0 + 256), a2 = CLMP(e0 + 512),
                      a3 = CLMP(e0 + 768), a4 = CLMP(e0 + 1024), a5 = CLMP(e0 + 1280),
                      a6 = CLMP(e0 + 1536), a7 = CLMP(e0 + 1792), a8 = CLMP(e0 + 2048),
                      a9 = CLMP(e0 + 2304);
            #undef CLMP
            // 10 independent unconditional loads, straight-line
            const fvec4 v0 = *(const fvec4*)(cls_base + 4 * a0);
            const fvec4 v1 = *(const fvec4*)(cls_base + 4 * a1);
            const fvec4 v2 = *(const fvec4*)(cls_base + 4 * a2);
            const fvec4 v3 = *(const fvec4*)(cls_base + 4 * a3);
            const fvec4 v4 = *(const fvec4*)(cls_base + 4 * a4);
            const fvec4 v5 = *(const fvec4*)(cls_base + 4 * a5);
            const fvec4 v6 = *(const fvec4*)(cls_base + 4 * a6);
            const fvec4 v7 = *(const fvec4*)(cls_base + 4 * a7);
            const fvec4 v8 = *(const fvec4*)(cls_base + 4 * a8);
            const fvec4 v9 = *(const fvec4*)(cls_base + 4 * a9);

            const float lbs[10] = {lb0,lb1,lb2,lb3,lb4,lb5,lb6,lb7,lb8,lb9};
            const fvec4 vs[10]  = {v0,v1,v2,v3,v4,v5,v6,v7,v8,v9};
            #pragma unroll
            for (int k = 0; k < 10; ++k) {
                const int e   = e0 + k * 256;
                const int c4  = e - (e / 20) * 20;
                const float lab  = lbs[k];
                const float mask = (lab >= 0.0f) ? 1.0f : 0.0f;
                const float pv[4] = { vs[k].x, vs[k].y, vs[k].z, vs[k].w };
                const float cb = (float)(c4 * 4 + 1);
                float local = 0.0f;
                #pragma unroll
                for (int j = 0; j < 4; ++j) {
                    const float p = fminf(fmaxf(pv[j], 1.0e-4f), 1.0f - 1.0e-4f);
                    const bool  is_pos = (lab == cb + (float)j);
                    const float pt     = is_pos ? p : 1.0f - p;
                    const float alpha  = is_pos ? 0.25f : 0.75f;
                    const float om     = 1.0f - pt;
                    local += alpha * om * om * (-__logf(pt));
                }
                cls_acc += mask * local;
            }
        }
    }

    // ---- block reduction: 3 values over 256 threads ----
    const int lane = t & 63, wid = t >> 6;
    #pragma unroll
    for (int off = 32; off > 0; off >>= 1) {
        cls_acc += __shfl_down(cls_acc, off, 64);
        reg_acc += __shfl_down(reg_acc, off, 64);
        pos_cnt += __shfl_down(pos_cnt, off, 64);
    }
    if (lane == 0) {
        s_red[wid]     = cls_acc;
        s_red[4 + wid] = reg_acc;
        s_red[8 + wid] = pos_cnt;
    }
    __syncthreads();
    if (t == 0) {
        const float c = s_red[0] + s_red[1] + s_red[2]  + s_red[3];
        const float r = s_red[4] + s_red[5] + s_red[6]  + s_red[7];
        const float p = s_red[8] + s_red[9] + s_red[10] + s_red[11];
        if (c != 0.0f) atomicAdd(&ws[b], c);
        if (r != 0.0f) atomicAdd(&ws[4 + b], r);
        if (p != 0.0f) atomicAdd(&ws[8 + b], p);
    }
}

__global__ void retina_final(const float* __restrict__ ws,
                             float* __restrict__ out, int B)
{
    if (threadIdx.x == 0 && blockIdx.x == 0) {
        float cl = 0.0f, rl = 0.0f, nv = 0.0f;
        for (int b = 0; b < B; ++b) {
            const float pos = ws[8 + b];
            if (pos > 0.0f) {
                cl += ws[b]     / fmaxf(pos, 1.0f);
                rl += ws[4 + b] / fmaxf(4.0f * pos, 1.0f);
                nv += 1.0f;
            }
        }
        const float n = fmaxf(nv, 1.0f);
        out[0] = cl / n;
        out[1] = rl / n;
    }
}

extern "C" void kernel_launch(void* const* d_in, const int* in_sizes, int n_in,
                              void* d_out, int out_size, void* d_ws, size_t ws_size,
                              hipStream_t stream) {
    const float* cls = (const float*)d_in[0];
    const float* reg = (const float*)d_in[1];
    const float* anc = (const float*)d_in[2];
    const float* ann = (const float*)d_in[3];

    const int B = 4;
    const int N = in_sizes[1] / (4 * B);      // 76725
    const int M = in_sizes[3] / (5 * B);      // 16
    float* ws = (float*)d_ws;

    (void)hipMemsetAsync(d_ws, 0, 12 * sizeof(float), stream);

    dim3 grid((N + 255) / 256, B);            // 300 x 4 = 1200 blocks
    retina_main<<<grid, 256, 0, stream>>>(cls, reg, anc, ann, ws, N, M, B);
    retina_final<<<1, 64, 0, stream>>>(ws, (float*)d_out, B);
}